// Round 1
// baseline (163.431 us; speedup 1.0000x reference)
//
#include <hip/hip_runtime.h>
#include <stdint.h>

#define NEGV (-1000000000.0f)

typedef float  f32x4  __attribute__((ext_vector_type(4)));
typedef __bf16 bf16x8 __attribute__((ext_vector_type(8)));

__device__ __forceinline__ unsigned short f2bf(float f){
  union { float f; unsigned u; } v; v.f = f;
  unsigned r = v.u + 0x7FFFu + ((v.u >> 16) & 1u);
  return (unsigned short)(r >> 16);
}
__device__ __forceinline__ unsigned packbf2(float a, float b){
  return (unsigned)f2bf(a) | ((unsigned)f2bf(b) << 16);
}
__device__ __forceinline__ void gl_lds16(const void* g, const char* l){
  __builtin_amdgcn_global_load_lds(
      (const __attribute__((address_space(1))) void*)g,
      (__attribute__((address_space(3))) void*)(unsigned)(uintptr_t)l,
      16, 0, 0);
}

// ---------------- K0: Q -> swizzled bf16 (row + transposed layouts), s_q ----
__global__ __launch_bounds__(256) void k0_prep(const float* __restrict__ Q,
                                               const float* __restrict__ w,
                                               char* __restrict__ qbf,
                                               char* __restrict__ qtbf,
                                               float* __restrict__ sq_ws)
{
  __shared__ float tile[128][129];
  __shared__ float sqs[128];
  const int b = blockIdx.x, t = threadIdx.x;
  if (t < 128) sqs[t] = 0.f;
  __syncthreads();
  for (int hc = 0; hc < 4; ++hc){
    // phase 1: coalesced load, row-layout bf16 store, s_q partials
    for (int it = 0; it < 16; ++it){
      int idx = it*256 + t;
      int j = idx >> 5, h4 = idx & 31;
      const f32x4 q4 = *(const f32x4*)(Q + ((size_t)b*128 + j)*512 + hc*128 + h4*4);
      *(f32x4*)(&tile[j][h4*4]) = q4;
      unsigned lo = packbf2(q4.x, q4.y), hi = packbf2(q4.z, q4.w);
      int o = ((j*256 + h4*8) ^ ((j & 7) << 4));
      char* dst = qbf + ((size_t)b*4 + hc)*32768 + o;
      *(unsigned*)dst = lo; *(unsigned*)(dst + 4) = hi;
      const float* w2 = w + 512 + hc*128 + h4*4;
      float p = q4.x*w2[0] + q4.y*w2[1] + q4.z*w2[2] + q4.w*w2[3];
      for (int s = 16; s > 0; s >>= 1) p += __shfl_down(p, s, 32);
      if ((t & 31) == 0) sqs[j] += p;
    }
    __syncthreads();
    // phase 2: transposed-layout bf16 store
    for (int it = 0; it < 32; ++it){
      int idx = it*256 + t;
      int hr = idx >> 6, j2 = idx & 63;
      float a = tile[j2*2][hr], c = tile[j2*2+1][hr];
      int o = ((hr*256 + j2*4) ^ ((hr & 7) << 4));
      *(unsigned*)(qtbf + ((size_t)b*4 + hc)*32768 + o) = packbf2(a, c);
    }
    __syncthreads();
  }
  if (t < 128) sq_ws[b*128 + t] = sqs[t];
}

// ---------------- K1: S^T mfma -> softmax -> PV mfma; A, C*A, B_vec partials
#define SM_QB 0
#define SM_CW 32768
#define SM_SCF 49152
#define SM_SQF (49152 + 256)
#define SM_EX  (49152 + 256 + 512)
#define SM_MSK (49152 + 256 + 512 + 256)
#define SM_TOT (49152 + 256 + 512 + 256 + 512)

__global__ __launch_bounds__(256, 3) void k1_main(
    const float* __restrict__ C, const int* __restrict__ qmask,
    const float* __restrict__ w, const float* __restrict__ sq_ws,
    const char* __restrict__ qbf, const char* __restrict__ qtbf,
    float* __restrict__ out, float* __restrict__ num_part,
    float* __restrict__ den_part)
{
  __shared__ __align__(16) char sm[SM_TOT];
  float* scf = (float*)(sm + SM_SCF);
  float* sqf = (float*)(sm + SM_SQF);
  float* exf = (float*)(sm + SM_EX);
  int*   msk = (int*)(sm + SM_MSK);

  const int t = threadIdx.x;
  const int b = blockIdx.y, itile = blockIdx.x;
  const int i0 = itile * 64;
  const int wv = t >> 6, ln = t & 63;
  const int g = ln >> 4, c16 = ln & 15;

  if (t < 64) scf[t] = 0.f;
  if (t < 128){ sqf[t] = sq_ws[b*128 + t]; msk[t] = qmask[b*128 + t]; }

  f32x4 acc[8] = {};
  const char* qsrc = qbf + (size_t)b * 131072;

  for (int kc = 0; kc < 4; ++kc){
    __syncthreads();
    { // stage Q chunk (pre-swizzled) via global_load_lds
      const char* src = qsrc + kc*32768;
      int base = wv*1024 + (ln << 4);
      #pragma unroll
      for (int r = 0; r < 8; ++r)
        gl_lds16(src + r*4096 + base, sm + SM_QB + r*4096 + wv*1024);
    }
    // stage C*w3 chunk -> bf16 swizzled, accumulate s_c partials
    #pragma unroll
    for (int u = 0; u < 8; ++u){
      int row = u*8 + (t >> 5), h4 = t & 31;
      const f32x4 c4  = *(const f32x4*)(C + ((size_t)(b*1024 + i0 + row))*512 + kc*128 + h4*4);
      const f32x4 w3v = *(const f32x4*)(w + 1024 + kc*128 + h4*4);
      const f32x4 w1v = *(const f32x4*)(w + kc*128 + h4*4);
      unsigned lo = packbf2(c4.x*w3v.x, c4.y*w3v.y);
      unsigned hi = packbf2(c4.z*w3v.z, c4.w*w3v.w);
      int o = ((row*256 + h4*8) ^ ((row & 7) << 4));
      *(unsigned*)(sm + SM_CW + o) = lo; *(unsigned*)(sm + SM_CW + o + 4) = hi;
      float p = c4.x*w1v.x + c4.y*w1v.y + c4.z*w1v.z + c4.w*w1v.w;
      for (int s = 16; s > 0; s >>= 1) p += __shfl_down(p, s, 32);
      if ((t & 31) == 0) scf[row] += p;
    }
    __syncthreads();
    // S^T = mfma(Q, Cw3): D[j][i], wave wv owns i-range 16*wv..+15
    #pragma unroll
    for (int ks = 0; ks < 4; ++ks){
      int kb = ks*64 + g*16;
      int irow = wv*16 + c16;
      bf16x8 bv = *(const bf16x8*)(sm + SM_CW + ((irow*256 + kb) ^ ((irow & 7) << 4)));
      #pragma unroll
      for (int mf = 0; mf < 8; ++mf){
        int j = mf*16 + c16;
        bf16x8 av = *(const bf16x8*)(sm + SM_QB + ((j*256 + kb) ^ ((j & 7) << 4)));
        acc[mf] = __builtin_amdgcn_mfma_f32_16x16x32_bf16(av, bv, acc[mf], 0, 0, 0);
      }
    }
  }
  __syncthreads();

  // per-row (i) softmax over j: lane owns col i=16*wv+c16, j spread over (mf,g,r)
  const int iloc = wv*16 + c16;
  float sc = scf[iloc];
  float m = -3.0e38f;
  #pragma unroll
  for (int mf = 0; mf < 8; ++mf)
    #pragma unroll
    for (int r = 0; r < 4; ++r){
      int j = mf*16 + g*4 + r;
      float v = msk[j] ? (acc[mf][r] + sc + sqf[j]) : NEGV;
      acc[mf][r] = v;
      m = fmaxf(m, v);
    }
  m = fmaxf(m, __shfl_xor(m, 16));
  m = fmaxf(m, __shfl_xor(m, 32));
  float s = 0.f;
  #pragma unroll
  for (int mf = 0; mf < 8; ++mf)
    #pragma unroll
    for (int r = 0; r < 4; ++r){
      float e = __expf(acc[mf][r] - m);
      acc[mf][r] = e; s += e;
    }
  s += __shfl_xor(s, 16);
  s += __shfl_xor(s, 32);
  float inv = 1.0f / s;
  // write normalized P (A-operand layout [i][j], swizzled) into CW region
  #pragma unroll
  for (int mf = 0; mf < 8; ++mf)
    #pragma unroll
    for (int r = 0; r < 4; ++r){
      int j = mf*16 + g*4 + r;
      int o = ((iloc*256 + j*2) ^ ((iloc & 7) << 4));
      *(unsigned short*)(sm + SM_CW + o) = f2bf(acc[mf][r] * inv);
    }
  if (g == 0) exf[iloc] = __expf(m);   // unnormalized exp(maxS[i])

  // PV: A = P @ Q, h in 4 chunks of 128 using transposed Q layout
  const char* qtsrc = qtbf + (size_t)b * 131072;
  for (int hc = 0; hc < 4; ++hc){
    if (hc) __syncthreads();
    {
      const char* src = qtsrc + hc*32768;
      int base = wv*1024 + (ln << 4);
      #pragma unroll
      for (int r = 0; r < 8; ++r)
        gl_lds16(src + r*4096 + base, sm + SM_QB + r*4096 + wv*1024);
    }
    __syncthreads();
    bf16x8 pa[4];
    #pragma unroll
    for (int ks = 0; ks < 4; ++ks){
      int kb = ks*64 + g*16;
      pa[ks] = *(const bf16x8*)(sm + SM_CW + ((iloc*256 + kb) ^ ((iloc & 7) << 4)));
    }
    f32x4 a2[8] = {};
    #pragma unroll
    for (int nf = 0; nf < 8; ++nf){
      int hr = nf*16 + c16;
      #pragma unroll
      for (int ks = 0; ks < 4; ++ks){
        int kb = ks*64 + g*16;
        bf16x8 bv = *(const bf16x8*)(sm + SM_QB + ((hr*256 + kb) ^ ((hr & 7) << 4)));
        a2[nf] = __builtin_amdgcn_mfma_f32_16x16x32_bf16(pa[ks], bv, a2[nf], 0, 0, 0);
      }
    }
    // write A and C*A
    #pragma unroll
    for (int nf = 0; nf < 8; ++nf){
      int h = hc*128 + nf*16 + c16;
      #pragma unroll
      for (int r = 0; r < 4; ++r){
        int i = wv*16 + g*4 + r;
        size_t rowb = (size_t)(b*1024 + i0 + i);
        float av = a2[nf][r];
        float cv = C[rowb*512 + h];
        out[rowb*2048 + 512 + h]  = av;
        out[rowb*2048 + 1024 + h] = cv * av;
      }
    }
    __syncthreads();
  }

  // B_vec partials: num = sum_i exp(maxS_i)*C[i,:], den = sum_i exp(maxS_i)
  float n0 = 0.f, n1 = 0.f;
  for (int i2 = 0; i2 < 64; ++i2){
    float e = exf[i2];
    size_t rowb = (size_t)(b*1024 + i0 + i2);
    n0 += e * C[rowb*512 + t];
    n1 += e * C[rowb*512 + t + 256];
  }
  float* np = num_part + ((size_t)(b*16 + itile))*512;
  np[t] = n0; np[t + 256] = n1;
  if (t < 64){
    float d = exf[t];
    for (int s2 = 32; s2 > 0; s2 >>= 1) d += __shfl_down(d, s2, 64);
    if (t == 0) den_part[b*16 + itile] = d;
  }
}

// ---------------- K2: reduce partials -> B_vec ------------------------------
__global__ __launch_bounds__(256) void k2_bvec(const float* __restrict__ num_part,
                                               const float* __restrict__ den_part,
                                               float* __restrict__ bvec)
{
  int b = blockIdx.x, t = threadIdx.x;
  float d = 0.f;
  for (int k = 0; k < 16; ++k) d += den_part[b*16 + k];
  float inv = 1.0f / d;
  for (int h = t; h < 512; h += 256){
    float s = 0.f;
    for (int k = 0; k < 16; ++k) s += num_part[(size_t)(b*16 + k)*512 + h];
    bvec[b*512 + h] = s * inv;
  }
}

// ---------------- K3: write C and C*B_vec chunks ----------------------------
__global__ __launch_bounds__(256) void k3_cout(const float* __restrict__ C,
                                               const float* __restrict__ bvec,
                                               float* __restrict__ out)
{
  int t = threadIdx.x;
  size_t row = (size_t)blockIdx.x*2 + (t >> 7);
  int col4 = t & 127;
  int b = (int)(row >> 10);
  const f32x4 c4 = *(const f32x4*)(C + row*512 + col4*4);
  const f32x4 bv = *(const f32x4*)(bvec + (size_t)b*512 + col4*4);
  f32x4* orow = (f32x4*)(out + row*2048);
  orow[col4] = c4;
  f32x4 cb;
  cb.x = c4.x*bv.x; cb.y = c4.y*bv.y; cb.z = c4.z*bv.z; cb.w = c4.w*bv.w;
  orow[384 + col4] = cb;
}

extern "C" void kernel_launch(void* const* d_in, const int* in_sizes, int n_in,
                              void* d_out, int out_size, void* d_ws, size_t ws_size,
                              hipStream_t stream)
{
  const float* C     = (const float*)d_in[0];
  const float* Q     = (const float*)d_in[1];
  const int*   qmask = (const int*)d_in[2];
  const float* w     = (const float*)d_in[3];
  float* out = (float*)d_out;
  char*  ws  = (char*)d_ws;

  char*  qbf      = ws;                                   // 4 MB
  char*  qtbf     = ws + (4 << 20);                       // 4 MB
  float* sq_ws    = (float*)(ws + (8 << 20));             // 16 KB
  float* num_part = (float*)(ws + (8 << 20) + (1 << 16)); // 1 MB
  float* den_part = (float*)(ws + (9 << 20) + (1 << 16)); // 2 KB
  float* bvec     = (float*)(ws + (9 << 20) + (1 << 16) + 4096); // 64 KB

  k0_prep<<<32, 256, 0, stream>>>(Q, w, qbf, qtbf, sq_ws);
  k1_main<<<dim3(16, 32), 256, 0, stream>>>(C, qmask, w, sq_ws, qbf, qtbf,
                                            out, num_part, den_part);
  k2_bvec<<<32, 256, 0, stream>>>(num_part, den_part, bvec);
  k3_cout<<<16384, 256, 0, stream>>>(C, bvec, out);
}

// Round 2
// 156.393 us; speedup vs baseline: 1.0450x; 1.0450x over previous
//
#include <hip/hip_runtime.h>
#include <stdint.h>

#define NEGV (-1000000000.0f)

typedef float  f32x4  __attribute__((ext_vector_type(4)));
typedef __bf16 bf16x8 __attribute__((ext_vector_type(8)));

__device__ __forceinline__ unsigned short f2bf(float f){
  union { float f; unsigned u; } v; v.f = f;
  unsigned r = v.u + 0x7FFFu + ((v.u >> 16) & 1u);
  return (unsigned short)(r >> 16);
}
__device__ __forceinline__ unsigned packbf2(float a, float b){
  return (unsigned)f2bf(a) | ((unsigned)f2bf(b) << 16);
}
__device__ __forceinline__ void gl_lds16(const void* g, const char* l){
  __builtin_amdgcn_global_load_lds(
      (const __attribute__((address_space(1))) void*)g,
      (__attribute__((address_space(3))) void*)(unsigned)(uintptr_t)l,
      16, 0, 0);
}

// Layouts in ws (per batch, 128 KB each):
//  qbf : 8 chunks of [128 j][64 k] bf16, row 128 B, swizzled  o^=((j&7)<<4)
//  qtbf: 8 chunks of [64 h][128 j] bf16, row 256 B, swizzled  o^=((h&7)<<4)

// ---------------- K0: Q -> swizzled bf16 (row + transposed layouts), s_q ----
__global__ __launch_bounds__(256) void k0_prep(const float* __restrict__ Q,
                                               const float* __restrict__ w,
                                               char* __restrict__ qbf,
                                               char* __restrict__ qtbf,
                                               float* __restrict__ sq_ws)
{
  __shared__ float tile[128][129];
  __shared__ float sqs[128];
  const int b = blockIdx.x, t = threadIdx.x;
  if (t < 128) sqs[t] = 0.f;
  __syncthreads();
  for (int hc = 0; hc < 4; ++hc){
    for (int it = 0; it < 16; ++it){
      int idx = it*256 + t;
      int j = idx >> 5, h4 = idx & 31;
      const f32x4 q4 = *(const f32x4*)(Q + ((size_t)b*128 + j)*512 + hc*128 + h4*4);
      *(f32x4*)(&tile[j][h4*4]) = q4;
      unsigned lo = packbf2(q4.x, q4.y), hi = packbf2(q4.z, q4.w);
      int k = hc*128 + h4*4;
      int o = (k >> 6)*16384 + ((j*128 + (k & 63)*2) ^ ((j & 7) << 4));
      char* dst = qbf + (size_t)b*131072 + o;
      *(unsigned*)dst = lo; *(unsigned*)(dst + 4) = hi;
      const float* w2 = w + 512 + k;
      float p = q4.x*w2[0] + q4.y*w2[1] + q4.z*w2[2] + q4.w*w2[3];
      for (int s = 16; s > 0; s >>= 1) p += __shfl_down(p, s, 32);
      if ((t & 31) == 0) sqs[j] += p;
    }
    __syncthreads();
    for (int it = 0; it < 32; ++it){
      int idx = it*256 + t;
      int hr = idx >> 6, j2 = idx & 63;
      float a = tile[j2*2][hr], c = tile[j2*2+1][hr];
      int h = hc*128 + hr;
      int o = (h >> 6)*16384 + (((h & 63)*256 + j2*4) ^ ((h & 7) << 4));
      *(unsigned*)(qtbf + (size_t)b*131072 + o) = packbf2(a, c);
    }
    __syncthreads();
  }
  if (t < 128) sq_ws[b*128 + t] = sqs[t];
}

// ---------------- K1 ----------------
#define SM_QB 0                      // 32 KB = 2 x 16 KB halves
#define SM_CW 32768                  // 16 KB = 2 x 8 KB halves (S) / P (PV)
#define SM_SCF 49152
#define SM_SQF (SM_SCF + 256)
#define SM_EX  (SM_SQF + 512)
#define SM_MSK (SM_EX + 256)
#define SM_TOT (SM_MSK + 512)

__global__ __launch_bounds__(256, 3) void k1_main(
    const float* __restrict__ C, const int* __restrict__ qmask,
    const float* __restrict__ w, const float* __restrict__ sq_ws,
    const char* __restrict__ qbf, const char* __restrict__ qtbf,
    float* __restrict__ out, float* __restrict__ num_part,
    float* __restrict__ den_part)
{
  __shared__ __align__(16) char sm[SM_TOT];
  float* scf = (float*)(sm + SM_SCF);
  float* sqf = (float*)(sm + SM_SQF);
  float* exf = (float*)(sm + SM_EX);
  int*   msk = (int*)(sm + SM_MSK);

  const int t = threadIdx.x;
  const int bid = blockIdx.x;
  const int xcd = bid & 7, jj = bid >> 3;
  const int b = xcd*4 + (jj >> 4), itile = jj & 15;   // batch locality per XCD
  const int i0 = itile * 64;
  const int wv = t >> 6, ln = t & 63;
  const int g = ln >> 4, c16 = ln & 15;
  const int iloc = wv*16 + c16;

  if (t < 64) scf[t] = 0.f;
  if (t < 128){ sqf[t] = sq_ws[b*128 + t]; msk[t] = qmask[b*128 + t]; }
  __syncthreads();

  const char* qsrc  = qbf  + (size_t)b * 131072;
  const char* qtsrc = qtbf + (size_t)b * 131072;
  const float* Crow = C + (size_t)(b*1024 + i0) * 512;

  auto stageQ = [&](const char* src, int ch, int half){
    const char* s = src + ch*16384;
    int so = wv*4096 + (ln << 4);
    #pragma unroll
    for (int r = 0; r < 4; ++r)
      gl_lds16(s + so + r*1024, sm + SM_QB + half*16384 + wv*4096 + r*1024);
  };
  auto stageC = [&](int ch, int half){
    #pragma unroll
    for (int u = 0; u < 4; ++u){
      int idx = u*256 + t;
      int row = idx >> 4, cp = idx & 15;
      int k = ch*64 + cp*4;
      const f32x4 c4  = *(const f32x4*)(Crow + (size_t)row*512 + k);
      const f32x4 w3v = *(const f32x4*)(w + 1024 + k);
      const f32x4 w1v = *(const f32x4*)(w + k);
      uint64_t pk = (uint64_t)packbf2(c4.x*w3v.x, c4.y*w3v.y)
                  | ((uint64_t)packbf2(c4.z*w3v.z, c4.w*w3v.w) << 32);
      *(uint64_t*)(sm + SM_CW + half*8192 + ((row*128 + cp*8) ^ ((row & 7) << 4))) = pk;
      float p = c4.x*w1v.x + c4.y*w1v.y + c4.z*w1v.z + c4.w*w1v.w;
      p += __shfl_down(p, 8, 16); p += __shfl_down(p, 4, 16);
      p += __shfl_down(p, 2, 16); p += __shfl_down(p, 1, 16);
      if ((t & 15) == 0) scf[row] += p;
    }
  };

  // ---- S = (C*w3) @ Q^T via mfma(Q_frag, Cw3_frag): D[j][i] ----
  f32x4 acc[8] = {};
  stageQ(qsrc, 0, 0); stageC(0, 0);
  __syncthreads();
  #pragma unroll
  for (int ch = 0; ch < 8; ++ch){
    const int cur = ch & 1;
    if (ch < 7){ stageQ(qsrc, ch+1, cur^1); stageC(ch+1, cur^1); }
    const char* qb = sm + SM_QB + cur*16384;
    const char* cw = sm + SM_CW + cur*8192;
    #pragma unroll
    for (int ks = 0; ks < 2; ++ks){
      int kb = ks*64 + g*16;
      bf16x8 bv = *(const bf16x8*)(cw + ((iloc*128 + kb) ^ ((iloc & 7) << 4)));
      #pragma unroll
      for (int mf = 0; mf < 8; ++mf){
        int j = mf*16 + c16;
        bf16x8 av = *(const bf16x8*)(qb + ((j*128 + kb) ^ ((j & 7) << 4)));
        acc[mf] = __builtin_amdgcn_mfma_f32_16x16x32_bf16(av, bv, acc[mf], 0, 0, 0);
      }
    }
    __syncthreads();
  }

  // prefetch PV chunk 0 (overlaps softmax VALU)
  stageQ(qtsrc, 0, 0);

  // ---- softmax over j per row i = iloc ----
  float sc = scf[iloc];
  float m = -3.0e38f;
  #pragma unroll
  for (int mf = 0; mf < 8; ++mf)
    #pragma unroll
    for (int r = 0; r < 4; ++r){
      int j = mf*16 + g*4 + r;
      float v = msk[j] ? (acc[mf][r] + sc + sqf[j]) : NEGV;
      acc[mf][r] = v;
      m = fmaxf(m, v);
    }
  m = fmaxf(m, __shfl_xor(m, 16));
  m = fmaxf(m, __shfl_xor(m, 32));
  float s = 0.f;
  #pragma unroll
  for (int mf = 0; mf < 8; ++mf)
    #pragma unroll
    for (int r = 0; r < 4; ++r){
      float e = __expf(acc[mf][r] - m);
      acc[mf][r] = e; s += e;
    }
  s += __shfl_xor(s, 16);
  s += __shfl_xor(s, 32);
  float inv = 1.0f / s;
  #pragma unroll
  for (int mf = 0; mf < 8; ++mf){
    uint64_t pk = (uint64_t)packbf2(acc[mf][0]*inv, acc[mf][1]*inv)
                | ((uint64_t)packbf2(acc[mf][2]*inv, acc[mf][3]*inv) << 32);
    *(uint64_t*)(sm + SM_CW + ((iloc*256 + mf*32 + g*8) ^ ((iloc & 7) << 4))) = pk;
  }
  if (g == 0) exf[iloc] = __expf(m);
  __syncthreads();

  // ---- PV: A = P @ Q, flipped operands -> D[h][i], f32x4 epilogue ----
  bf16x8 pb[4];
  #pragma unroll
  for (int ks = 0; ks < 4; ++ks)
    pb[ks] = *(const bf16x8*)(sm + SM_CW + ((iloc*256 + ks*64 + g*16) ^ ((iloc & 7) << 4)));

  const size_t rowb = (size_t)(b*1024 + i0 + iloc);
  #pragma unroll
  for (int hch = 0; hch < 8; ++hch){
    const int cur = hch & 1;
    if (hch < 7) stageQ(qtsrc, hch+1, cur^1);
    const char* qb = sm + SM_QB + cur*16384;
    f32x4 a2[4] = {};
    #pragma unroll
    for (int nf = 0; nf < 4; ++nf){
      int hr = nf*16 + c16;
      #pragma unroll
      for (int ks = 0; ks < 4; ++ks){
        bf16x8 qa = *(const bf16x8*)(qb + ((hr*256 + ks*64 + g*16) ^ ((hr & 7) << 4)));
        a2[nf] = __builtin_amdgcn_mfma_f32_16x16x32_bf16(qa, pb[ks], a2[nf], 0, 0, 0);
      }
    }
    #pragma unroll
    for (int nf = 0; nf < 4; ++nf){
      int h = hch*64 + nf*16 + g*4;
      const f32x4 c4 = *(const f32x4*)(C + rowb*512 + h);
      f32x4 av = a2[nf];
      *(f32x4*)(out + rowb*2048 + 512 + h) = av;
      f32x4 ca; ca.x = av.x*c4.x; ca.y = av.y*c4.y; ca.z = av.z*c4.z; ca.w = av.w*c4.w;
      *(f32x4*)(out + rowb*2048 + 1024 + h) = ca;
    }
    __syncthreads();
  }

  // ---- B_vec partials ----
  float n0 = 0.f, n1 = 0.f;
  for (int i2 = 0; i2 < 64; ++i2){
    float e = exf[i2];
    const float* cr = C + (size_t)(b*1024 + i0 + i2)*512;
    n0 += e * cr[t];
    n1 += e * cr[t + 256];
  }
  float* np = num_part + ((size_t)(b*16 + itile))*512;
  np[t] = n0; np[t + 256] = n1;
  if (t < 64){
    float d = exf[t];
    for (int s2 = 32; s2 > 0; s2 >>= 1) d += __shfl_down(d, s2, 64);
    if (t == 0) den_part[b*16 + itile] = d;
  }
}

// ---------------- K2: reduce partials -> B_vec ------------------------------
__global__ __launch_bounds__(256) void k2_bvec(const float* __restrict__ num_part,
                                               const float* __restrict__ den_part,
                                               float* __restrict__ bvec)
{
  int b = blockIdx.x, t = threadIdx.x;
  float d = 0.f;
  for (int k = 0; k < 16; ++k) d += den_part[b*16 + k];
  float inv = 1.0f / d;
  for (int h = t; h < 512; h += 256){
    float s = 0.f;
    for (int k = 0; k < 16; ++k) s += num_part[(size_t)(b*16 + k)*512 + h];
    bvec[b*512 + h] = s * inv;
  }
}

// ---------------- K3: write C and C*B_vec chunks ----------------------------
__global__ __launch_bounds__(256) void k3_cout(const float* __restrict__ C,
                                               const float* __restrict__ bvec,
                                               float* __restrict__ out)
{
  int t = threadIdx.x;
  size_t row = (size_t)blockIdx.x*2 + (t >> 7);
  int col4 = t & 127;
  int b = (int)(row >> 10);
  const f32x4 c4 = *(const f32x4*)(C + row*512 + col4*4);
  const f32x4 bv = *(const f32x4*)(bvec + (size_t)b*512 + col4*4);
  f32x4* orow = (f32x4*)(out + row*2048);
  orow[col4] = c4;
  f32x4 cb;
  cb.x = c4.x*bv.x; cb.y = c4.y*bv.y; cb.z = c4.z*bv.z; cb.w = c4.w*bv.w;
  orow[384 + col4] = cb;
}

extern "C" void kernel_launch(void* const* d_in, const int* in_sizes, int n_in,
                              void* d_out, int out_size, void* d_ws, size_t ws_size,
                              hipStream_t stream)
{
  const float* C     = (const float*)d_in[0];
  const float* Q     = (const float*)d_in[1];
  const int*   qmask = (const int*)d_in[2];
  const float* w     = (const float*)d_in[3];
  float* out = (float*)d_out;
  char*  ws  = (char*)d_ws;

  char*  qbf      = ws;                                   // 4 MB
  char*  qtbf     = ws + (4 << 20);                       // 4 MB
  float* sq_ws    = (float*)(ws + (8 << 20));             // 16 KB
  float* num_part = (float*)(ws + (8 << 20) + (1 << 16)); // 1 MB
  float* den_part = (float*)(ws + (9 << 20) + (1 << 16)); // 2 KB
  float* bvec     = (float*)(ws + (9 << 20) + (1 << 16) + 4096); // 64 KB

  k0_prep<<<32, 256, 0, stream>>>(Q, w, qbf, qtbf, sq_ws);
  k1_main<<<512, 256, 0, stream>>>(C, qmask, w, sq_ws, qbf, qtbf,
                                   out, num_part, den_part);
  k2_bvec<<<32, 256, 0, stream>>>(num_part, den_part, bvec);
  k3_cout<<<16384, 256, 0, stream>>>(C, bvec, out);
}